// Round 1
// baseline (849.926 us; speedup 1.0000x reference)
//
#include <hip/hip_runtime.h>
#include <math.h>

#define NQ 100000
#define NL 32
#define QD 384
#define LD 1024
#define H 128
#define E_TOT 1000000
#define E_SEE 750000
#define E_PRED 250000
#define NN (NQ + NL)          // 100032
#define EPS 1e-5f

#define NB_SCAN ((NN + 255) / 256)    // 391
#define NB_GEMM ((NN + 127) / 128)    // 782
#define NB_XINI ((NQ + 127) / 128)    // 782

// ---------------- CSR build ----------------

__global__ void k_ew_hist(const int* __restrict__ ecs, const int* __restrict__ EI,
                          const float* __restrict__ ewt, const float* __restrict__ Wem,
                          const float* __restrict__ bem, float* __restrict__ ew,
                          int* __restrict__ cnt) {
  int e = blockIdx.x * 256 + threadIdx.x;
  if (e >= E_SEE) return;
  int idx = ecs[e];
  int d = EI[E_TOT + idx];
  atomicAdd(&cnt[d], 1);
  float w = ewt[idx] * Wem[0] + bem[0];
  ew[e] = w > 0.f ? w : 0.01f * w;
}

__global__ void k_scan_block(const int* __restrict__ cnt, int* __restrict__ bsum) {
  __shared__ int red[256];
  int i = blockIdx.x * 256 + threadIdx.x;
  red[threadIdx.x] = (i < NN) ? cnt[i] : 0;
  __syncthreads();
  for (int s = 128; s > 0; s >>= 1) {
    if (threadIdx.x < s) red[threadIdx.x] += red[threadIdx.x + s];
    __syncthreads();
  }
  if (threadIdx.x == 0) bsum[blockIdx.x] = red[0];
}

__global__ void k_scan_top(const int* __restrict__ bsum, int* __restrict__ boff) {
  __shared__ int buf[2][512];
  int t = threadIdx.x;
  int v = (t < NB_SCAN) ? bsum[t] : 0;
  buf[0][t] = v;
  __syncthreads();
  int src = 0;
  for (int d = 1; d < 512; d <<= 1) {
    int x = buf[src][t];
    if (t >= d) x += buf[src][t - d];
    buf[src ^ 1][t] = x;
    __syncthreads();
    src ^= 1;
  }
  if (t < NB_SCAN) boff[t] = buf[src][t] - v;  // exclusive
}

__global__ void k_scan_write(const int* __restrict__ cnt, const int* __restrict__ boff,
                             int* __restrict__ off) {
  __shared__ int buf[2][256];
  int t = threadIdx.x;
  int i = blockIdx.x * 256 + t;
  int v = (i < NN) ? cnt[i] : 0;
  buf[0][t] = v;
  __syncthreads();
  int src = 0;
  for (int d = 1; d < 256; d <<= 1) {
    int x = buf[src][t];
    if (t >= d) x += buf[src][t - d];
    buf[src ^ 1][t] = x;
    __syncthreads();
    src ^= 1;
  }
  if (i < NN) off[i] = boff[blockIdx.x] + buf[src][t] - v;
  if (i == 0) off[NN] = E_SEE;
}

__global__ void k_fill(const int* __restrict__ ecs, const int* __restrict__ EI,
                       const float* __restrict__ ew, const int* __restrict__ off,
                       int* __restrict__ cur, int* __restrict__ csr_src,
                       float* __restrict__ csr_ew) {
  int e = blockIdx.x * 256 + threadIdx.x;
  if (e >= E_SEE) return;
  int idx = ecs[e];
  int s = EI[idx];
  int d = EI[E_TOT + idx];
  int p = off[d] + atomicAdd(&cur[d], 1);
  csr_src[p] = s;
  csr_ew[p] = ew[e];
}

// ---------------- x_ini = [qf@Wq+bq ; lf@Wl+bl] ----------------

__global__ __launch_bounds__(256) void k_xini(
    const float* __restrict__ qf, const float* __restrict__ lf,
    const float* __restrict__ Wq, const float* __restrict__ bq,
    const float* __restrict__ Wl, const float* __restrict__ bl,
    float* __restrict__ XINI) {
  if ((int)blockIdx.x < NB_XINI) {
    __shared__ float sA[16][132];
    __shared__ float sB[16][128];
    int tid = threadIdx.x;
    int tx = tid & 15, ty = tid >> 4;
    int rowbase = blockIdx.x * 128;
    float c[8][8];
#pragma unroll
    for (int i = 0; i < 8; i++)
#pragma unroll
      for (int j = 0; j < 8; j++) c[i][j] = 0.f;
    for (int kb = 0; kb < QD; kb += 16) {
#pragma unroll
      for (int p = 0; p < 2; ++p) {
        int f = tid + p * 256;
        int row = f >> 2;
        int kq = (f & 3) << 2;
        int gr = rowbase + row;
        float4 v = make_float4(0.f, 0.f, 0.f, 0.f);
        if (gr < NQ) v = *(const float4*)&qf[(size_t)gr * QD + kb + kq];
        sA[kq + 0][row] = v.x; sA[kq + 1][row] = v.y;
        sA[kq + 2][row] = v.z; sA[kq + 3][row] = v.w;
      }
#pragma unroll
      for (int p = 0; p < 2; ++p) {
        int f = tid + p * 256;
        int k = f >> 5;
        int cq = (f & 31) << 2;
        *(float4*)&sB[k][cq] = *(const float4*)&Wq[(size_t)(kb + k) * H + cq];
      }
      __syncthreads();
#pragma unroll
      for (int k = 0; k < 16; ++k) {
        float4 a0 = *(const float4*)&sA[k][ty * 8];
        float4 a1 = *(const float4*)&sA[k][ty * 8 + 4];
        float4 b0 = *(const float4*)&sB[k][tx * 8];
        float4 b1 = *(const float4*)&sB[k][tx * 8 + 4];
        float av[8] = {a0.x, a0.y, a0.z, a0.w, a1.x, a1.y, a1.z, a1.w};
        float bv[8] = {b0.x, b0.y, b0.z, b0.w, b1.x, b1.y, b1.z, b1.w};
#pragma unroll
        for (int i = 0; i < 8; i++)
#pragma unroll
          for (int j = 0; j < 8; j++) c[i][j] = fmaf(av[i], bv[j], c[i][j]);
      }
      __syncthreads();
    }
    int c0 = tx * 8;
    float4 q0 = *(const float4*)&bq[c0];
    float4 q1 = *(const float4*)&bq[c0 + 4];
    float bb[8] = {q0.x, q0.y, q0.z, q0.w, q1.x, q1.y, q1.z, q1.w};
#pragma unroll
    for (int i = 0; i < 8; i++) {
      int n = rowbase + ty * 8 + i;
      if (n >= NQ) continue;
      float o[8];
#pragma unroll
      for (int j = 0; j < 8; j++) o[j] = c[i][j] + bb[j];
      *(float4*)&XINI[(size_t)n * H + c0] = make_float4(o[0], o[1], o[2], o[3]);
      *(float4*)&XINI[(size_t)n * H + c0 + 4] = make_float4(o[4], o[5], o[6], o[7]);
    }
  } else {
    // llm rows: 32 x (K=1024) @ Wl -> 128 cols; one block per row, thread = col
    int r = blockIdx.x - NB_XINI;
    int t = threadIdx.x;
    if (r >= NL || t >= H) return;
    float acc = 0.f;
    for (int k = 0; k < LD; k += 4) {
      float a0 = lf[(size_t)r * LD + k + 0];
      float a1 = lf[(size_t)r * LD + k + 1];
      float a2 = lf[(size_t)r * LD + k + 2];
      float a3 = lf[(size_t)r * LD + k + 3];
      acc = fmaf(a0, Wl[(size_t)(k + 0) * H + t], acc);
      acc = fmaf(a1, Wl[(size_t)(k + 1) * H + t], acc);
      acc = fmaf(a2, Wl[(size_t)(k + 2) * H + t], acc);
      acc = fmaf(a3, Wl[(size_t)(k + 3) * H + t], acc);
    }
    XINI[(size_t)(NQ + r) * H + t] = acc + bl[t];
  }
}

// ---------------- segment sum (one wave per node) ----------------
// TRANS: apply lrelu(scale*x + shift) to gathered rows (layer-2 consumes BN1 lazily)

template <bool TRANS>
__global__ __launch_bounds__(256) void k_seg(
    const float* __restrict__ Xin, const int* __restrict__ off,
    const int* __restrict__ csr_src, const float* __restrict__ csr_ew,
    const float* __restrict__ scale, const float* __restrict__ shift,
    float* __restrict__ S, float* __restrict__ swsum, float* __restrict__ degf) {
  int w = blockIdx.x * 4 + (threadIdx.x >> 6);
  if (w >= NN) return;
  int lane = threadIdx.x & 63;
  int o0 = off[w], o1 = off[w + 1];
  float ax = 1.f, ay = 1.f, bx = 0.f, by = 0.f;
  if (TRANS) {
    float2 sc = *(const float2*)&scale[lane * 2];
    float2 sh = *(const float2*)&shift[lane * 2];
    ax = sc.x; ay = sc.y; bx = sh.x; by = sh.y;
  }
  float accx = 0.f, accy = 0.f, ews = 0.f;
  for (int k = o0; k < o1; ++k) {
    int s = csr_src[k];
    float2 v = *(const float2*)&Xin[(size_t)s * H + lane * 2];
    if (TRANS) {
      float t0 = fmaf(ax, v.x, bx); v.x = t0 > 0.f ? t0 : 0.01f * t0;
      float t1 = fmaf(ay, v.y, by); v.y = t1 > 0.f ? t1 : 0.01f * t1;
    }
    accx += v.x; accy += v.y;
    ews += csr_ew[k];
  }
  *(float2*)&S[(size_t)w * H + lane * 2] = make_float2(accx, accy);
  if (lane == 0) { swsum[w] = ews; degf[w] = (float)(o1 - o0); }
}

// ---------------- node GEMM + residual + BN partial stats ----------------
// out = S@W + deg*(bm+be) + swsum*We + resid(in),  resid: TRANS ? lrelu(a*in+b) : in
// also emits per-block column sum/sumsq partials of out (for BN of THIS layer).

template <bool TRANS>
__global__ __launch_bounds__(256) void k_gemm(
    const float* __restrict__ S, const float* __restrict__ Xin,
    float* __restrict__ Xout, const float* __restrict__ W,
    const float* __restrict__ bm, const float* __restrict__ be,
    const float* __restrict__ We,
    const float* __restrict__ scale, const float* __restrict__ shift,
    const float* __restrict__ swsum, const float* __restrict__ degf,
    float* __restrict__ partials) {
  __shared__ float sA[16][132];
  __shared__ float sB[16][128];
  __shared__ float st[2][16][128];
  int tid = threadIdx.x;
  int tx = tid & 15, ty = tid >> 4;
  int rowbase = blockIdx.x * 128;
  float c[8][8];
#pragma unroll
  for (int i = 0; i < 8; i++)
#pragma unroll
    for (int j = 0; j < 8; j++) c[i][j] = 0.f;
  for (int kb = 0; kb < H; kb += 16) {
#pragma unroll
    for (int p = 0; p < 2; ++p) {
      int f = tid + p * 256;
      int row = f >> 2;
      int kq = (f & 3) << 2;
      int gr = rowbase + row;
      float4 v = make_float4(0.f, 0.f, 0.f, 0.f);
      if (gr < NN) v = *(const float4*)&S[(size_t)gr * H + kb + kq];
      sA[kq + 0][row] = v.x; sA[kq + 1][row] = v.y;
      sA[kq + 2][row] = v.z; sA[kq + 3][row] = v.w;
    }
#pragma unroll
    for (int p = 0; p < 2; ++p) {
      int f = tid + p * 256;
      int k = f >> 5;
      int cq = (f & 31) << 2;
      *(float4*)&sB[k][cq] = *(const float4*)&W[(size_t)(kb + k) * H + cq];
    }
    __syncthreads();
#pragma unroll
    for (int k = 0; k < 16; ++k) {
      float4 a0 = *(const float4*)&sA[k][ty * 8];
      float4 a1 = *(const float4*)&sA[k][ty * 8 + 4];
      float4 b0 = *(const float4*)&sB[k][tx * 8];
      float4 b1 = *(const float4*)&sB[k][tx * 8 + 4];
      float av[8] = {a0.x, a0.y, a0.z, a0.w, a1.x, a1.y, a1.z, a1.w};
      float bv[8] = {b0.x, b0.y, b0.z, b0.w, b1.x, b1.y, b1.z, b1.w};
#pragma unroll
      for (int i = 0; i < 8; i++)
#pragma unroll
        for (int j = 0; j < 8; j++) c[i][j] = fmaf(av[i], bv[j], c[i][j]);
    }
    __syncthreads();
  }
  int c0 = tx * 8;
  float cb[8], we[8], sc[8], sh[8];
  {
    float4 m0 = *(const float4*)&bm[c0];
    float4 m1 = *(const float4*)&bm[c0 + 4];
    float4 e0 = *(const float4*)&be[c0];
    float4 e1 = *(const float4*)&be[c0 + 4];
    cb[0] = m0.x + e0.x; cb[1] = m0.y + e0.y; cb[2] = m0.z + e0.z; cb[3] = m0.w + e0.w;
    cb[4] = m1.x + e1.x; cb[5] = m1.y + e1.y; cb[6] = m1.z + e1.z; cb[7] = m1.w + e1.w;
    float4 w0 = *(const float4*)&We[c0];
    float4 w1 = *(const float4*)&We[c0 + 4];
    we[0] = w0.x; we[1] = w0.y; we[2] = w0.z; we[3] = w0.w;
    we[4] = w1.x; we[5] = w1.y; we[6] = w1.z; we[7] = w1.w;
    if (TRANS) {
      float4 s0 = *(const float4*)&scale[c0];
      float4 s1 = *(const float4*)&scale[c0 + 4];
      float4 h0 = *(const float4*)&shift[c0];
      float4 h1 = *(const float4*)&shift[c0 + 4];
      sc[0] = s0.x; sc[1] = s0.y; sc[2] = s0.z; sc[3] = s0.w;
      sc[4] = s1.x; sc[5] = s1.y; sc[6] = s1.z; sc[7] = s1.w;
      sh[0] = h0.x; sh[1] = h0.y; sh[2] = h0.z; sh[3] = h0.w;
      sh[4] = h1.x; sh[5] = h1.y; sh[6] = h1.z; sh[7] = h1.w;
    }
  }
  float ps[8], pss[8];
#pragma unroll
  for (int j = 0; j < 8; j++) { ps[j] = 0.f; pss[j] = 0.f; }
#pragma unroll
  for (int i = 0; i < 8; i++) {
    int n = rowbase + ty * 8 + i;
    if (n < NN) {
      float dg = degf[n], sw = swsum[n];
      float4 r0 = *(const float4*)&Xin[(size_t)n * H + c0];
      float4 r1 = *(const float4*)&Xin[(size_t)n * H + c0 + 4];
      float rr[8] = {r0.x, r0.y, r0.z, r0.w, r1.x, r1.y, r1.z, r1.w};
      if (TRANS) {
#pragma unroll
        for (int j = 0; j < 8; j++) {
          float t = fmaf(sc[j], rr[j], sh[j]);
          rr[j] = t > 0.f ? t : 0.01f * t;
        }
      }
      float o[8];
#pragma unroll
      for (int j = 0; j < 8; j++) {
        o[j] = c[i][j] + dg * cb[j] + sw * we[j] + rr[j];
        ps[j] += o[j];
        pss[j] += o[j] * o[j];
      }
      *(float4*)&Xout[(size_t)n * H + c0] = make_float4(o[0], o[1], o[2], o[3]);
      *(float4*)&Xout[(size_t)n * H + c0 + 4] = make_float4(o[4], o[5], o[6], o[7]);
    }
  }
  *(float4*)&st[0][ty][c0] = make_float4(ps[0], ps[1], ps[2], ps[3]);
  *(float4*)&st[0][ty][c0 + 4] = make_float4(ps[4], ps[5], ps[6], ps[7]);
  *(float4*)&st[1][ty][c0] = make_float4(pss[0], pss[1], pss[2], pss[3]);
  *(float4*)&st[1][ty][c0 + 4] = make_float4(pss[4], pss[5], pss[6], pss[7]);
  __syncthreads();
  int stt = tid >> 7, col = tid & 127;
  float s = 0.f;
#pragma unroll
  for (int y = 0; y < 16; y++) s += st[stt][y][col];
  partials[(size_t)blockIdx.x * 256 + tid] = s;
}

// ---------------- BN stats finish: scale/shift per column ----------------

__global__ void k_bnstats(const float* __restrict__ partials,
                          const float* __restrict__ g, const float* __restrict__ beta,
                          float* __restrict__ scale, float* __restrict__ shift) {
  __shared__ float s[256];
  int t = threadIdx.x;
  float acc = 0.f;
  for (int b = 0; b < NB_GEMM; ++b) acc += partials[(size_t)b * 256 + t];
  s[t] = acc;
  __syncthreads();
  if (t < H) {
    float mean = s[t] / (float)NN;
    float var = s[128 + t] / (float)NN - mean * mean;
    float a = g[t] * rsqrtf(var + EPS);
    scale[t] = a;
    shift[t] = beta[t] - mean * a;
  }
}

// ---------------- edge predict (one wave per edge) ----------------

__global__ __launch_bounds__(256) void k_pred(
    const int* __restrict__ emask, const int* __restrict__ EI,
    const float* __restrict__ XINI, const float* __restrict__ X,
    const float* __restrict__ scale, const float* __restrict__ shift,
    float* __restrict__ out) {
  int i = blockIdx.x * 4 + (threadIdx.x >> 6);
  if (i >= E_PRED) return;
  int lane = threadIdx.x & 63;
  int m = emask[i];
  int p0 = EI[m];
  int p1 = EI[E_TOT + m];
  float2 a = *(const float2*)&XINI[(size_t)p0 * H + lane * 2];
  float2 b = *(const float2*)&X[(size_t)p1 * H + lane * 2];
  float2 sc = *(const float2*)&scale[lane * 2];
  float2 sh = *(const float2*)&shift[lane * 2];
  float v = a.x * fmaf(sc.x, b.x, sh.x) + a.y * fmaf(sc.y, b.y, sh.y);
#pragma unroll
  for (int mm = 32; mm > 0; mm >>= 1) v += __shfl_xor(v, mm, 64);
  if (lane == 0) out[i] = 1.f / (1.f + expf(-v * (1.f / 128.f)));
}

// ---------------- launcher ----------------

extern "C" void kernel_launch(void* const* d_in, const int* in_sizes, int n_in,
                              void* d_out, int out_size, void* d_ws, size_t ws_size,
                              hipStream_t stream) {
  const float* qf    = (const float*)d_in[0];
  const float* lf    = (const float*)d_in[1];
  const int*   EI    = (const int*)d_in[2];
  const int*   emask = (const int*)d_in[3];
  const int*   ecs   = (const int*)d_in[4];
  const float* ewt   = (const float*)d_in[5];
  const float* Wq    = (const float*)d_in[6];
  const float* bq    = (const float*)d_in[7];
  const float* Wl    = (const float*)d_in[8];
  const float* bl    = (const float*)d_in[9];
  const float* Wem   = (const float*)d_in[10];
  const float* bem   = (const float*)d_in[11];
  const float* W1m   = (const float*)d_in[12];
  const float* b1m   = (const float*)d_in[13];
  const float* W1e   = (const float*)d_in[14];
  const float* b1e   = (const float*)d_in[15];
  const float* W2m   = (const float*)d_in[16];
  const float* b2m   = (const float*)d_in[17];
  const float* W2e   = (const float*)d_in[18];
  const float* b2e   = (const float*)d_in[19];
  const float* g1    = (const float*)d_in[20];
  const float* beta1 = (const float*)d_in[21];
  const float* g2    = (const float*)d_in[22];
  const float* beta2 = (const float*)d_in[23];
  float* out = (float*)d_out;

  char* p = (char*)d_ws;
  auto alloc = [&](size_t bytes) -> void* {
    void* r = (void*)p;
    p += (bytes + 255) & ~(size_t)255;
    return r;
  };
  float* XINI    = (float*)alloc((size_t)NN * H * 4);
  float* X       = (float*)alloc((size_t)NN * H * 4);
  float* S       = (float*)alloc((size_t)NN * H * 4);
  float* ew      = (float*)alloc((size_t)E_SEE * 4);
  float* csr_ew  = (float*)alloc((size_t)E_SEE * 4);
  int*   csr_src = (int*)alloc((size_t)E_SEE * 4);
  int*   cnt     = (int*)alloc((size_t)NN * 4);
  int*   off     = (int*)alloc((size_t)(NN + 1) * 4);
  int*   cur     = (int*)alloc((size_t)NN * 4);
  int*   bsum    = (int*)alloc((size_t)NB_SCAN * 4);
  int*   boff    = (int*)alloc((size_t)NB_SCAN * 4);
  float* swsum   = (float*)alloc((size_t)NN * 4);
  float* degf    = (float*)alloc((size_t)NN * 4);
  float* partials= (float*)alloc((size_t)NB_GEMM * 256 * 4);
  float* scale1  = (float*)alloc(128 * 4);
  float* shift1  = (float*)alloc(128 * 4);
  float* scale2  = (float*)alloc(128 * 4);
  float* shift2  = (float*)alloc(128 * 4);

  hipMemsetAsync(cnt, 0, (size_t)NN * 4, stream);
  hipMemsetAsync(cur, 0, (size_t)NN * 4, stream);

  int ebl = (E_SEE + 255) / 256;
  k_ew_hist<<<ebl, 256, 0, stream>>>(ecs, EI, ewt, Wem, bem, ew, cnt);
  k_scan_block<<<NB_SCAN, 256, 0, stream>>>(cnt, bsum);
  k_scan_top<<<1, 512, 0, stream>>>(bsum, boff);
  k_scan_write<<<NB_SCAN, 256, 0, stream>>>(cnt, boff, off);
  k_fill<<<ebl, 256, 0, stream>>>(ecs, EI, ew, off, cur, csr_src, csr_ew);

  k_xini<<<NB_XINI + NL, 256, 0, stream>>>(qf, lf, Wq, bq, Wl, bl, XINI);

  int segbl = (NN + 3) / 4;
  // layer 1
  k_seg<false><<<segbl, 256, 0, stream>>>(XINI, off, csr_src, csr_ew,
                                          nullptr, nullptr, S, swsum, degf);
  k_gemm<false><<<NB_GEMM, 256, 0, stream>>>(S, XINI, X, W1m, b1m, b1e, W1e,
                                             nullptr, nullptr, swsum, degf, partials);
  k_bnstats<<<1, 256, 0, stream>>>(partials, g1, beta1, scale1, shift1);
  // layer 2 (BN1+lrelu folded into gather & residual)
  k_seg<true><<<segbl, 256, 0, stream>>>(X, off, csr_src, csr_ew,
                                         scale1, shift1, S, swsum, degf);
  k_gemm<true><<<NB_GEMM, 256, 0, stream>>>(S, X, X, W2m, b2m, b2e, W2e,
                                            scale1, shift1, swsum, degf, partials);
  k_bnstats<<<1, 256, 0, stream>>>(partials, g2, beta2, scale2, shift2);
  // predict (BN2 folded in)
  int pbl = (E_PRED + 3) / 4;
  k_pred<<<pbl, 256, 0, stream>>>(emask, EI, XINI, X, scale2, shift2, out);
}

// Round 2
// 825.059 us; speedup vs baseline: 1.0301x; 1.0301x over previous
//
#include <hip/hip_runtime.h>
#include <math.h>

#define NQ 100000
#define NL 32
#define QD 384
#define LD 1024
#define H 128
#define E_TOT 1000000
#define E_SEE 750000
#define E_PRED 250000
#define NN (NQ + NL)          // 100032
#define EPS 1e-5f

#define NB_SCAN ((NN + 255) / 256)    // 391
#define NB_GEMM ((NN + 127) / 128)    // 782
#define NB_XINI ((NQ + 127) / 128)    // 782

typedef __attribute__((ext_vector_type(8))) short short8;
typedef __attribute__((ext_vector_type(4))) short short4v;
typedef __attribute__((ext_vector_type(4))) float f32x4;

__device__ __forceinline__ unsigned short f2bf(float f) {
  unsigned int u = __builtin_bit_cast(unsigned int, f);
  u = (u + 0x7FFFu + ((u >> 16) & 1u)) >> 16;
  return (unsigned short)u;
}

// ---------------- CSR build ----------------

__global__ void k_ew_hist(const int* __restrict__ ecs, const int* __restrict__ EI,
                          const float* __restrict__ ewt, const float* __restrict__ Wem,
                          const float* __restrict__ bem, float* __restrict__ ew,
                          int* __restrict__ cnt) {
  int e = blockIdx.x * 256 + threadIdx.x;
  if (e >= E_SEE) return;
  int idx = ecs[e];
  int d = EI[E_TOT + idx];
  atomicAdd(&cnt[d], 1);
  float w = ewt[idx] * Wem[0] + bem[0];
  ew[e] = w > 0.f ? w : 0.01f * w;
}

__global__ void k_scan_block(const int* __restrict__ cnt, int* __restrict__ bsum) {
  __shared__ int red[256];
  int i = blockIdx.x * 256 + threadIdx.x;
  red[threadIdx.x] = (i < NN) ? cnt[i] : 0;
  __syncthreads();
  for (int s = 128; s > 0; s >>= 1) {
    if (threadIdx.x < s) red[threadIdx.x] += red[threadIdx.x + s];
    __syncthreads();
  }
  if (threadIdx.x == 0) bsum[blockIdx.x] = red[0];
}

__global__ void k_scan_top(const int* __restrict__ bsum, int* __restrict__ boff) {
  __shared__ int buf[2][512];
  int t = threadIdx.x;
  int v = (t < NB_SCAN) ? bsum[t] : 0;
  buf[0][t] = v;
  __syncthreads();
  int src = 0;
  for (int d = 1; d < 512; d <<= 1) {
    int x = buf[src][t];
    if (t >= d) x += buf[src][t - d];
    buf[src ^ 1][t] = x;
    __syncthreads();
    src ^= 1;
  }
  if (t < NB_SCAN) boff[t] = buf[src][t] - v;  // exclusive
}

__global__ void k_scan_write(const int* __restrict__ cnt, const int* __restrict__ boff,
                             int* __restrict__ off) {
  __shared__ int buf[2][256];
  int t = threadIdx.x;
  int i = blockIdx.x * 256 + t;
  int v = (i < NN) ? cnt[i] : 0;
  buf[0][t] = v;
  __syncthreads();
  int src = 0;
  for (int d = 1; d < 256; d <<= 1) {
    int x = buf[src][t];
    if (t >= d) x += buf[src][t - d];
    buf[src ^ 1][t] = x;
    __syncthreads();
    src ^= 1;
  }
  if (i < NN) off[i] = boff[blockIdx.x] + buf[src][t] - v;
  if (i == 0) off[NN] = E_SEE;
}

__global__ void k_fill(const int* __restrict__ ecs, const int* __restrict__ EI,
                       const float* __restrict__ ew, const int* __restrict__ off,
                       int* __restrict__ cur, int* __restrict__ csr_src,
                       float* __restrict__ csr_ew) {
  int e = blockIdx.x * 256 + threadIdx.x;
  if (e >= E_SEE) return;
  int idx = ecs[e];
  int s = EI[idx];
  int d = EI[E_TOT + idx];
  int p = off[d] + atomicAdd(&cur[d], 1);
  csr_src[p] = s;
  csr_ew[p] = ew[e];
}

// ---------------- prep: Wq^T in bf16, [n][k] (k contiguous) ----------------

__global__ void k_prep_wqt(const float* __restrict__ Wq, unsigned short* __restrict__ Wqt) {
  // Wq is [QD][H]; Wqt is [H][QD]
  for (int i = blockIdx.x * 256 + threadIdx.x; i < QD * H; i += gridDim.x * 256) {
    int n = i / QD, k = i - n * QD;
    Wqt[i] = f2bf(Wq[(size_t)k * H + n]);
  }
}

// ---------------- x_ini = [qf@Wq+bq ; lf@Wl+bl] (bf16 MFMA for q rows) ------

__global__ __launch_bounds__(256) void k_xini(
    const float* __restrict__ qf, const float* __restrict__ lf,
    const unsigned short* __restrict__ Wqt, const float* __restrict__ bq,
    const float* __restrict__ Wl, const float* __restrict__ bl,
    float* __restrict__ XINI) {
  if ((int)blockIdx.x < NB_XINI) {
    // 128 rows x 128 cols, K=384 in BK=32 steps. 4 waves, 64x64 quadrant each,
    // 4x4 grid of mfma_f32_16x16x32_bf16.
    __shared__ unsigned short sA[128][40];  // pad 32->40: 20-dword row stride, 2-way max
    __shared__ unsigned short sB[128][40];
    int tid = threadIdx.x;
    int w = tid >> 6, lane = tid & 63;
    int l15 = lane & 15, quad = lane >> 4;
    int wr = (w >> 1) * 64, wc = (w & 1) * 64;
    int rowbase = blockIdx.x * 128;
    f32x4 acc[4][4];
#pragma unroll
    for (int i = 0; i < 4; i++)
#pragma unroll
      for (int j = 0; j < 4; j++) acc[i][j] = (f32x4){0.f, 0.f, 0.f, 0.f};

    for (int kb = 0; kb < QD; kb += 32) {
      // stage A: rows rowbase..+128, k kb..+32 (fp32 -> bf16)
#pragma unroll
      for (int pass = 0; pass < 4; ++pass) {
        int row = pass * 32 + (tid >> 3);
        int kc = (tid & 7) * 4;
        int gr = rowbase + row;
        float4 v = make_float4(0.f, 0.f, 0.f, 0.f);
        if (gr < NQ) v = *(const float4*)&qf[(size_t)gr * QD + kb + kc];
        short4v b;
        b.x = (short)f2bf(v.x); b.y = (short)f2bf(v.y);
        b.z = (short)f2bf(v.z); b.w = (short)f2bf(v.w);
        *(short4v*)&sA[row][kc] = b;
      }
      // stage B: Wqt[n][kb..+32), bf16, 16B chunks
#pragma unroll
      for (int pass = 0; pass < 2; ++pass) {
        int n = pass * 64 + (tid >> 2);
        int k8 = (tid & 3) * 8;
        *(int4*)&sB[n][k8] = *(const int4*)&Wqt[(size_t)n * QD + kb + k8];
      }
      __syncthreads();
      short8 af[4], bfr[4];
#pragma unroll
      for (int mt = 0; mt < 4; ++mt)
        af[mt] = *(const short8*)&sA[wr + mt * 16 + l15][quad * 8];
#pragma unroll
      for (int nt = 0; nt < 4; ++nt)
        bfr[nt] = *(const short8*)&sB[wc + nt * 16 + l15][quad * 8];
#pragma unroll
      for (int mt = 0; mt < 4; ++mt)
#pragma unroll
        for (int nt = 0; nt < 4; ++nt)
          acc[mt][nt] = __builtin_amdgcn_mfma_f32_16x16x32_bf16(
              af[mt], bfr[nt], acc[mt][nt], 0, 0, 0);
      __syncthreads();
    }
    // epilogue: + bq, store. C/D: col = l15, row = quad*4 + r
#pragma unroll
    for (int nt = 0; nt < 4; ++nt) {
      int col = wc + nt * 16 + l15;
      float bias = bq[col];
#pragma unroll
      for (int mt = 0; mt < 4; ++mt) {
#pragma unroll
        for (int r = 0; r < 4; ++r) {
          int n = rowbase + wr + mt * 16 + quad * 4 + r;
          if (n < NQ) XINI[(size_t)n * H + col] = acc[mt][nt][r] + bias;
        }
      }
    }
  } else {
    // llm rows: 32 x (K=1024) @ Wl -> 128 cols; one block per row, thread = col
    int r = blockIdx.x - NB_XINI;
    int t = threadIdx.x;
    if (r >= NL || t >= H) return;
    float acc = 0.f;
    for (int k = 0; k < LD; k += 4) {
      float a0 = lf[(size_t)r * LD + k + 0];
      float a1 = lf[(size_t)r * LD + k + 1];
      float a2 = lf[(size_t)r * LD + k + 2];
      float a3 = lf[(size_t)r * LD + k + 3];
      acc = fmaf(a0, Wl[(size_t)(k + 0) * H + t], acc);
      acc = fmaf(a1, Wl[(size_t)(k + 1) * H + t], acc);
      acc = fmaf(a2, Wl[(size_t)(k + 2) * H + t], acc);
      acc = fmaf(a3, Wl[(size_t)(k + 3) * H + t], acc);
    }
    XINI[(size_t)(NQ + r) * H + t] = acc + bl[t];
  }
}

// ---------------- segment sum (one wave per node) ----------------
// TRANS: apply lrelu(scale*x + shift) to gathered rows (layer-2 consumes BN1 lazily)

template <bool TRANS>
__global__ __launch_bounds__(256) void k_seg(
    const float* __restrict__ Xin, const int* __restrict__ off,
    const int* __restrict__ csr_src, const float* __restrict__ csr_ew,
    const float* __restrict__ scale, const float* __restrict__ shift,
    float* __restrict__ S, float* __restrict__ swsum, float* __restrict__ degf) {
  int w = blockIdx.x * 4 + (threadIdx.x >> 6);
  if (w >= NN) return;
  int lane = threadIdx.x & 63;
  int o0 = off[w], o1 = off[w + 1];
  float ax = 1.f, ay = 1.f, bx = 0.f, by = 0.f;
  if (TRANS) {
    float2 sc = *(const float2*)&scale[lane * 2];
    float2 sh = *(const float2*)&shift[lane * 2];
    ax = sc.x; ay = sc.y; bx = sh.x; by = sh.y;
  }
  float accx = 0.f, accy = 0.f, ews = 0.f;
  for (int k = o0; k < o1; ++k) {
    int s = csr_src[k];
    float2 v = *(const float2*)&Xin[(size_t)s * H + lane * 2];
    if (TRANS) {
      float t0 = fmaf(ax, v.x, bx); v.x = t0 > 0.f ? t0 : 0.01f * t0;
      float t1 = fmaf(ay, v.y, by); v.y = t1 > 0.f ? t1 : 0.01f * t1;
    }
    accx += v.x; accy += v.y;
    ews += csr_ew[k];
  }
  *(float2*)&S[(size_t)w * H + lane * 2] = make_float2(accx, accy);
  if (lane == 0) { swsum[w] = ews; degf[w] = (float)(o1 - o0); }
}

// ---------------- node GEMM + residual + BN partial stats ----------------

template <bool TRANS>
__global__ __launch_bounds__(256) void k_gemm(
    const float* __restrict__ S, const float* __restrict__ Xin,
    float* __restrict__ Xout, const float* __restrict__ W,
    const float* __restrict__ bm, const float* __restrict__ be,
    const float* __restrict__ We,
    const float* __restrict__ scale, const float* __restrict__ shift,
    const float* __restrict__ swsum, const float* __restrict__ degf,
    float* __restrict__ partials) {
  __shared__ float sA[16][132];
  __shared__ float sB[16][128];
  __shared__ float st[2][16][128];
  int tid = threadIdx.x;
  int tx = tid & 15, ty = tid >> 4;
  int rowbase = blockIdx.x * 128;
  float c[8][8];
#pragma unroll
  for (int i = 0; i < 8; i++)
#pragma unroll
    for (int j = 0; j < 8; j++) c[i][j] = 0.f;
  for (int kb = 0; kb < H; kb += 16) {
#pragma unroll
    for (int p = 0; p < 2; ++p) {
      int f = tid + p * 256;
      int row = f >> 2;
      int kq = (f & 3) << 2;
      int gr = rowbase + row;
      float4 v = make_float4(0.f, 0.f, 0.f, 0.f);
      if (gr < NN) v = *(const float4*)&S[(size_t)gr * H + kb + kq];
      sA[kq + 0][row] = v.x; sA[kq + 1][row] = v.y;
      sA[kq + 2][row] = v.z; sA[kq + 3][row] = v.w;
    }
#pragma unroll
    for (int p = 0; p < 2; ++p) {
      int f = tid + p * 256;
      int k = f >> 5;
      int cq = (f & 31) << 2;
      *(float4*)&sB[k][cq] = *(const float4*)&W[(size_t)(kb + k) * H + cq];
    }
    __syncthreads();
#pragma unroll
    for (int k = 0; k < 16; ++k) {
      float4 a0 = *(const float4*)&sA[k][ty * 8];
      float4 a1 = *(const float4*)&sA[k][ty * 8 + 4];
      float4 b0 = *(const float4*)&sB[k][tx * 8];
      float4 b1 = *(const float4*)&sB[k][tx * 8 + 4];
      float av[8] = {a0.x, a0.y, a0.z, a0.w, a1.x, a1.y, a1.z, a1.w};
      float bv[8] = {b0.x, b0.y, b0.z, b0.w, b1.x, b1.y, b1.z, b1.w};
#pragma unroll
      for (int i = 0; i < 8; i++)
#pragma unroll
        for (int j = 0; j < 8; j++) c[i][j] = fmaf(av[i], bv[j], c[i][j]);
    }
    __syncthreads();
  }
  int c0 = tx * 8;
  float cb[8], we[8], sc[8], sh[8];
  {
    float4 m0 = *(const float4*)&bm[c0];
    float4 m1 = *(const float4*)&bm[c0 + 4];
    float4 e0 = *(const float4*)&be[c0];
    float4 e1 = *(const float4*)&be[c0 + 4];
    cb[0] = m0.x + e0.x; cb[1] = m0.y + e0.y; cb[2] = m0.z + e0.z; cb[3] = m0.w + e0.w;
    cb[4] = m1.x + e1.x; cb[5] = m1.y + e1.y; cb[6] = m1.z + e1.z; cb[7] = m1.w + e1.w;
    float4 w0 = *(const float4*)&We[c0];
    float4 w1 = *(const float4*)&We[c0 + 4];
    we[0] = w0.x; we[1] = w0.y; we[2] = w0.z; we[3] = w0.w;
    we[4] = w1.x; we[5] = w1.y; we[6] = w1.z; we[7] = w1.w;
    if (TRANS) {
      float4 s0 = *(const float4*)&scale[c0];
      float4 s1 = *(const float4*)&scale[c0 + 4];
      float4 h0 = *(const float4*)&shift[c0];
      float4 h1 = *(const float4*)&shift[c0 + 4];
      sc[0] = s0.x; sc[1] = s0.y; sc[2] = s0.z; sc[3] = s0.w;
      sc[4] = s1.x; sc[5] = s1.y; sc[6] = s1.z; sc[7] = s1.w;
      sh[0] = h0.x; sh[1] = h0.y; sh[2] = h0.z; sh[3] = h0.w;
      sh[4] = h1.x; sh[5] = h1.y; sh[6] = h1.z; sh[7] = h1.w;
    }
  }
  float ps[8], pss[8];
#pragma unroll
  for (int j = 0; j < 8; j++) { ps[j] = 0.f; pss[j] = 0.f; }
#pragma unroll
  for (int i = 0; i < 8; i++) {
    int n = rowbase + ty * 8 + i;
    if (n < NN) {
      float dg = degf[n], sw = swsum[n];
      float4 r0 = *(const float4*)&Xin[(size_t)n * H + c0];
      float4 r1 = *(const float4*)&Xin[(size_t)n * H + c0 + 4];
      float rr[8] = {r0.x, r0.y, r0.z, r0.w, r1.x, r1.y, r1.z, r1.w};
      if (TRANS) {
#pragma unroll
        for (int j = 0; j < 8; j++) {
          float t = fmaf(sc[j], rr[j], sh[j]);
          rr[j] = t > 0.f ? t : 0.01f * t;
        }
      }
      float o[8];
#pragma unroll
      for (int j = 0; j < 8; j++) {
        o[j] = c[i][j] + dg * cb[j] + sw * we[j] + rr[j];
        ps[j] += o[j];
        pss[j] += o[j] * o[j];
      }
      *(float4*)&Xout[(size_t)n * H + c0] = make_float4(o[0], o[1], o[2], o[3]);
      *(float4*)&Xout[(size_t)n * H + c0 + 4] = make_float4(o[4], o[5], o[6], o[7]);
    }
  }
  *(float4*)&st[0][ty][c0] = make_float4(ps[0], ps[1], ps[2], ps[3]);
  *(float4*)&st[0][ty][c0 + 4] = make_float4(ps[4], ps[5], ps[6], ps[7]);
  *(float4*)&st[1][ty][c0] = make_float4(pss[0], pss[1], pss[2], pss[3]);
  *(float4*)&st[1][ty][c0 + 4] = make_float4(pss[4], pss[5], pss[6], pss[7]);
  __syncthreads();
  int stt = tid >> 7, col = tid & 127;
  float s = 0.f;
#pragma unroll
  for (int y = 0; y < 16; y++) s += st[stt][y][col];
  partials[(size_t)blockIdx.x * 256 + tid] = s;
}

// ---------------- BN stats finish: scale/shift per column ----------------

__global__ void k_bnstats(const float* __restrict__ partials,
                          const float* __restrict__ g, const float* __restrict__ beta,
                          float* __restrict__ scale, float* __restrict__ shift) {
  __shared__ float s[256];
  int t = threadIdx.x;
  float acc = 0.f;
  for (int b = 0; b < NB_GEMM; ++b) acc += partials[(size_t)b * 256 + t];
  s[t] = acc;
  __syncthreads();
  if (t < H) {
    float mean = s[t] / (float)NN;
    float var = s[128 + t] / (float)NN - mean * mean;
    float a = g[t] * rsqrtf(var + EPS);
    scale[t] = a;
    shift[t] = beta[t] - mean * a;
  }
}

// ---------------- edge predict (one wave per edge) ----------------

__global__ __launch_bounds__(256) void k_pred(
    const int* __restrict__ emask, const int* __restrict__ EI,
    const float* __restrict__ XINI, const float* __restrict__ X,
    const float* __restrict__ scale, const float* __restrict__ shift,
    float* __restrict__ out) {
  int i = blockIdx.x * 4 + (threadIdx.x >> 6);
  if (i >= E_PRED) return;
  int lane = threadIdx.x & 63;
  int m = emask[i];
  int p0 = EI[m];
  int p1 = EI[E_TOT + m];
  float2 a = *(const float2*)&XINI[(size_t)p0 * H + lane * 2];
  float2 b = *(const float2*)&X[(size_t)p1 * H + lane * 2];
  float2 sc = *(const float2*)&scale[lane * 2];
  float2 sh = *(const float2*)&shift[lane * 2];
  float v = a.x * fmaf(sc.x, b.x, sh.x) + a.y * fmaf(sc.y, b.y, sh.y);
#pragma unroll
  for (int mm = 32; mm > 0; mm >>= 1) v += __shfl_xor(v, mm, 64);
  if (lane == 0) out[i] = 1.f / (1.f + expf(-v * (1.f / 128.f)));
}

// ---------------- launcher ----------------

extern "C" void kernel_launch(void* const* d_in, const int* in_sizes, int n_in,
                              void* d_out, int out_size, void* d_ws, size_t ws_size,
                              hipStream_t stream) {
  const float* qf    = (const float*)d_in[0];
  const float* lf    = (const float*)d_in[1];
  const int*   EI    = (const int*)d_in[2];
  const int*   emask = (const int*)d_in[3];
  const int*   ecs   = (const int*)d_in[4];
  const float* ewt   = (const float*)d_in[5];
  const float* Wq    = (const float*)d_in[6];
  const float* bq    = (const float*)d_in[7];
  const float* Wl    = (const float*)d_in[8];
  const float* bl    = (const float*)d_in[9];
  const float* Wem   = (const float*)d_in[10];
  const float* bem   = (const float*)d_in[11];
  const float* W1m   = (const float*)d_in[12];
  const float* b1m   = (const float*)d_in[13];
  const float* W1e   = (const float*)d_in[14];
  const float* b1e   = (const float*)d_in[15];
  const float* W2m   = (const float*)d_in[16];
  const float* b2m   = (const float*)d_in[17];
  const float* W2e   = (const float*)d_in[18];
  const float* b2e   = (const float*)d_in[19];
  const float* g1    = (const float*)d_in[20];
  const float* beta1 = (const float*)d_in[21];
  const float* g2    = (const float*)d_in[22];
  const float* beta2 = (const float*)d_in[23];
  float* out = (float*)d_out;

  char* p = (char*)d_ws;
  auto alloc = [&](size_t bytes) -> void* {
    void* r = (void*)p;
    p += (bytes + 255) & ~(size_t)255;
    return r;
  };
  float* XINI    = (float*)alloc((size_t)NN * H * 4);
  float* X       = (float*)alloc((size_t)NN * H * 4);
  float* S       = (float*)alloc((size_t)NN * H * 4);
  float* ew      = (float*)alloc((size_t)E_SEE * 4);
  float* csr_ew  = (float*)alloc((size_t)E_SEE * 4);
  int*   csr_src = (int*)alloc((size_t)E_SEE * 4);
  int*   cnt     = (int*)alloc((size_t)NN * 4);
  int*   off     = (int*)alloc((size_t)(NN + 1) * 4);
  int*   cur     = (int*)alloc((size_t)NN * 4);
  int*   bsum    = (int*)alloc((size_t)NB_SCAN * 4);
  int*   boff    = (int*)alloc((size_t)NB_SCAN * 4);
  float* swsum   = (float*)alloc((size_t)NN * 4);
  float* degf    = (float*)alloc((size_t)NN * 4);
  float* partials= (float*)alloc((size_t)NB_GEMM * 256 * 4);
  float* scale1  = (float*)alloc(128 * 4);
  float* shift1  = (float*)alloc(128 * 4);
  float* scale2  = (float*)alloc(128 * 4);
  float* shift2  = (float*)alloc(128 * 4);
  unsigned short* Wqt = (unsigned short*)alloc((size_t)QD * H * 2);

  hipMemsetAsync(cnt, 0, (size_t)NN * 4, stream);
  hipMemsetAsync(cur, 0, (size_t)NN * 4, stream);

  int ebl = (E_SEE + 255) / 256;
  k_prep_wqt<<<48, 256, 0, stream>>>(Wq, Wqt);
  k_ew_hist<<<ebl, 256, 0, stream>>>(ecs, EI, ewt, Wem, bem, ew, cnt);
  k_scan_block<<<NB_SCAN, 256, 0, stream>>>(cnt, bsum);
  k_scan_top<<<1, 512, 0, stream>>>(bsum, boff);
  k_scan_write<<<NB_SCAN, 256, 0, stream>>>(cnt, boff, off);
  k_fill<<<ebl, 256, 0, stream>>>(ecs, EI, ew, off, cur, csr_src, csr_ew);

  k_xini<<<NB_XINI + NL, 256, 0, stream>>>(qf, lf, Wqt, bq, Wl, bl, XINI);

  int segbl = (NN + 3) / 4;
  // layer 1
  k_seg<false><<<segbl, 256, 0, stream>>>(XINI, off, csr_src, csr_ew,
                                          nullptr, nullptr, S, swsum, degf);
  k_gemm<false><<<NB_GEMM, 256, 0, stream>>>(S, XINI, X, W1m, b1m, b1e, W1e,
                                             nullptr, nullptr, swsum, degf, partials);
  k_bnstats<<<1, 256, 0, stream>>>(partials, g1, beta1, scale1, shift1);
  // layer 2 (BN1+lrelu folded into gather & residual)
  k_seg<true><<<segbl, 256, 0, stream>>>(X, off, csr_src, csr_ew,
                                         scale1, shift1, S, swsum, degf);
  k_gemm<true><<<NB_GEMM, 256, 0, stream>>>(S, X, X, W2m, b2m, b2e, W2e,
                                            scale1, shift1, swsum, degf, partials);
  k_bnstats<<<1, 256, 0, stream>>>(partials, g2, beta2, scale2, shift2);
  // predict (BN2 folded in)
  int pbl = (E_PRED + 3) / 4;
  k_pred<<<pbl, 256, 0, stream>>>(emask, EI, XINI, X, scale2, shift2, out);
}

// Round 3
// 724.520 us; speedup vs baseline: 1.1731x; 1.1388x over previous
//
#include <hip/hip_runtime.h>
#include <math.h>

#define NQ 100000
#define NL 32
#define QD 384
#define LD 1024
#define H 128
#define E_TOT 1000000
#define E_SEE 750000
#define E_PRED 250000
#define NN (NQ + NL)          // 100032
#define EPS 1e-5f

#define NB_SCAN ((NN + 255) / 256)    // 391
#define NB_GEMM ((NN + 127) / 128)    // 782
#define NB_XINI ((NQ + 127) / 128)    // 782

typedef __attribute__((ext_vector_type(8))) short short8;
typedef __attribute__((ext_vector_type(4))) short short4v;
typedef __attribute__((ext_vector_type(4))) float f32x4;

__device__ __forceinline__ unsigned short f2bf(float f) {
  unsigned int u = __builtin_bit_cast(unsigned int, f);
  u = (u + 0x7FFFu + ((u >> 16) & 1u)) >> 16;
  return (unsigned short)u;
}

// ---------------- CSR build ----------------

__global__ void k_ew_hist(const int* __restrict__ ecs, const int* __restrict__ EI,
                          const float* __restrict__ ewt, const float* __restrict__ Wem,
                          const float* __restrict__ bem, float* __restrict__ ew,
                          int* __restrict__ cnt) {
  int e = blockIdx.x * 256 + threadIdx.x;
  if (e >= E_SEE) return;
  int idx = ecs[e];
  int d = EI[E_TOT + idx];
  atomicAdd(&cnt[d], 1);
  float w = ewt[idx] * Wem[0] + bem[0];
  ew[e] = w > 0.f ? w : 0.01f * w;
}

__global__ void k_scan_block(const int* __restrict__ cnt, int* __restrict__ bsum) {
  __shared__ int red[256];
  int i = blockIdx.x * 256 + threadIdx.x;
  red[threadIdx.x] = (i < NN) ? cnt[i] : 0;
  __syncthreads();
  for (int s = 128; s > 0; s >>= 1) {
    if (threadIdx.x < s) red[threadIdx.x] += red[threadIdx.x + s];
    __syncthreads();
  }
  if (threadIdx.x == 0) bsum[blockIdx.x] = red[0];
}

__global__ void k_scan_top(const int* __restrict__ bsum, int* __restrict__ boff) {
  __shared__ int buf[2][512];
  int t = threadIdx.x;
  int v = (t < NB_SCAN) ? bsum[t] : 0;
  buf[0][t] = v;
  __syncthreads();
  int src = 0;
  for (int d = 1; d < 512; d <<= 1) {
    int x = buf[src][t];
    if (t >= d) x += buf[src][t - d];
    buf[src ^ 1][t] = x;
    __syncthreads();
    src ^= 1;
  }
  if (t < NB_SCAN) boff[t] = buf[src][t] - v;  // exclusive
}

__global__ void k_scan_write(const int* __restrict__ cnt, const int* __restrict__ boff,
                             int* __restrict__ off) {
  __shared__ int buf[2][256];
  int t = threadIdx.x;
  int i = blockIdx.x * 256 + t;
  int v = (i < NN) ? cnt[i] : 0;
  buf[0][t] = v;
  __syncthreads();
  int src = 0;
  for (int d = 1; d < 256; d <<= 1) {
    int x = buf[src][t];
    if (t >= d) x += buf[src][t - d];
    buf[src ^ 1][t] = x;
    __syncthreads();
    src ^= 1;
  }
  if (i < NN) off[i] = boff[blockIdx.x] + buf[src][t] - v;
  if (i == 0) off[NN] = E_SEE;
}

__global__ void k_fill(const int* __restrict__ ecs, const int* __restrict__ EI,
                       const float* __restrict__ ew, const int* __restrict__ off,
                       int* __restrict__ cur, int* __restrict__ csr_src,
                       float* __restrict__ csr_ew) {
  int e = blockIdx.x * 256 + threadIdx.x;
  if (e >= E_SEE) return;
  int idx = ecs[e];
  int s = EI[idx];
  int d = EI[E_TOT + idx];
  int p = off[d] + atomicAdd(&cur[d], 1);
  csr_src[p] = s;
  csr_ew[p] = ew[e];
}

// ---------------- prep: bf16 transposed weights [n][k] ----------------

__global__ void k_prep(const float* __restrict__ Wq, const float* __restrict__ W1m,
                       const float* __restrict__ W2m,
                       unsigned short* __restrict__ Wqt, unsigned short* __restrict__ W1t,
                       unsigned short* __restrict__ W2t) {
  int i = blockIdx.x * 256 + threadIdx.x;  // grid covers 81920
  const int tot1 = QD * H;                 // 49152
  const int tot2 = H * H;                  // 16384
  if (i < tot1) {
    int n = i / QD, k = i - n * QD;
    Wqt[i] = f2bf(Wq[(size_t)k * H + n]);
  } else if (i < tot1 + tot2) {
    int j = i - tot1;
    int n = j >> 7, k = j & 127;
    W1t[j] = f2bf(W1m[(size_t)k * H + n]);
  } else if (i < tot1 + 2 * tot2) {
    int j = i - tot1 - tot2;
    int n = j >> 7, k = j & 127;
    W2t[j] = f2bf(W2m[(size_t)k * H + n]);
  }
}

// ---------------- llm rows: split-K partial + combine ----------------

__global__ __launch_bounds__(128) void k_llm_part(const float* __restrict__ lf,
                                                  const float* __restrict__ Wl,
                                                  float* __restrict__ part) {
  int r = blockIdx.x >> 3;   // 0..31
  int s = blockIdx.x & 7;    // 0..7
  int t = threadIdx.x;       // col 0..127
  int k0 = s * 128;
  float acc = 0.f;
#pragma unroll 4
  for (int k = 0; k < 128; k += 4) {
    float a0 = lf[(size_t)r * LD + k0 + k + 0];
    float a1 = lf[(size_t)r * LD + k0 + k + 1];
    float a2 = lf[(size_t)r * LD + k0 + k + 2];
    float a3 = lf[(size_t)r * LD + k0 + k + 3];
    acc = fmaf(a0, Wl[(size_t)(k0 + k + 0) * H + t], acc);
    acc = fmaf(a1, Wl[(size_t)(k0 + k + 1) * H + t], acc);
    acc = fmaf(a2, Wl[(size_t)(k0 + k + 2) * H + t], acc);
    acc = fmaf(a3, Wl[(size_t)(k0 + k + 3) * H + t], acc);
  }
  part[(size_t)blockIdx.x * 128 + t] = acc;
}

__global__ void k_llm_comb(const float* __restrict__ part, const float* __restrict__ bl,
                           float* __restrict__ XINI) {
  int i = blockIdx.x * 256 + threadIdx.x;
  if (i >= NL * H) return;
  int r = i >> 7, t = i & 127;
  float a = bl[t];
#pragma unroll
  for (int s = 0; s < 8; s++) a += part[(size_t)(r * 8 + s) * 128 + t];
  XINI[(size_t)(NQ + r) * H + t] = a;
}

// ---------------- x_ini q rows: bf16 MFMA 128x128 tile, K=384 ----------------

__global__ __launch_bounds__(256) void k_xini(
    const float* __restrict__ qf, const unsigned short* __restrict__ Wqt,
    const float* __restrict__ bq, float* __restrict__ XINI) {
  __shared__ unsigned short sA[128][40];  // pad: 20-dword stride
  __shared__ unsigned short sB[128][40];
  int tid = threadIdx.x;
  int w = tid >> 6, lane = tid & 63;
  int l15 = lane & 15, quad = lane >> 4;
  int wr = (w >> 1) * 64, wc = (w & 1) * 64;
  int rowbase = blockIdx.x * 128;
  f32x4 acc[4][4];
#pragma unroll
  for (int i = 0; i < 4; i++)
#pragma unroll
    for (int j = 0; j < 4; j++) acc[i][j] = (f32x4){0.f, 0.f, 0.f, 0.f};

  int arow = tid >> 3, akc = (tid & 7) * 4;
  int bn = tid >> 2, bk8 = (tid & 3) * 8;
  float4 pa[4];
  int4 pb[2];
  // preload step 0
#pragma unroll
  for (int p = 0; p < 4; ++p) {
    int gr = rowbase + p * 32 + arow;
    pa[p] = (gr < NQ) ? *(const float4*)&qf[(size_t)gr * QD + akc]
                      : make_float4(0.f, 0.f, 0.f, 0.f);
  }
#pragma unroll
  for (int p = 0; p < 2; ++p)
    pb[p] = *(const int4*)&Wqt[(size_t)(p * 64 + bn) * QD + bk8];

  for (int step = 0; step < 12; ++step) {
    int kb = step * 32;
    // write LDS from prefetch regs
#pragma unroll
    for (int p = 0; p < 4; ++p) {
      short4v b;
      b.x = (short)f2bf(pa[p].x); b.y = (short)f2bf(pa[p].y);
      b.z = (short)f2bf(pa[p].z); b.w = (short)f2bf(pa[p].w);
      *(short4v*)&sA[p * 32 + arow][akc] = b;
    }
#pragma unroll
    for (int p = 0; p < 2; ++p) *(int4*)&sB[p * 64 + bn][bk8] = pb[p];
    __syncthreads();
    if (step + 1 < 12) {
      int kn = kb + 32;
#pragma unroll
      for (int p = 0; p < 4; ++p) {
        int gr = rowbase + p * 32 + arow;
        pa[p] = (gr < NQ) ? *(const float4*)&qf[(size_t)gr * QD + kn + akc]
                          : make_float4(0.f, 0.f, 0.f, 0.f);
      }
#pragma unroll
      for (int p = 0; p < 2; ++p)
        pb[p] = *(const int4*)&Wqt[(size_t)(p * 64 + bn) * QD + kn + bk8];
    }
    short8 af[4], bfr[4];
#pragma unroll
    for (int mt = 0; mt < 4; ++mt)
      af[mt] = *(const short8*)&sA[wr + mt * 16 + l15][quad * 8];
#pragma unroll
    for (int nt = 0; nt < 4; ++nt)
      bfr[nt] = *(const short8*)&sB[wc + nt * 16 + l15][quad * 8];
#pragma unroll
    for (int mt = 0; mt < 4; ++mt)
#pragma unroll
      for (int nt = 0; nt < 4; ++nt)
        acc[mt][nt] = __builtin_amdgcn_mfma_f32_16x16x32_bf16(
            af[mt], bfr[nt], acc[mt][nt], 0, 0, 0);
    __syncthreads();
  }
#pragma unroll
  for (int nt = 0; nt < 4; ++nt) {
    int col = wc + nt * 16 + l15;
    float bias = bq[col];
#pragma unroll
    for (int mt = 0; mt < 4; ++mt) {
#pragma unroll
      for (int r = 0; r < 4; ++r) {
        int n = rowbase + wr + mt * 16 + quad * 4 + r;
        if (n < NQ) XINI[(size_t)n * H + col] = acc[mt][nt][r] + bias;
      }
    }
  }
}

// ---------------- segment sum (one wave per node), S stored bf16 ----------------

template <bool TRANS>
__global__ __launch_bounds__(256) void k_seg(
    const float* __restrict__ Xin, const int* __restrict__ off,
    const int* __restrict__ csr_src, const float* __restrict__ csr_ew,
    const float* __restrict__ scale, const float* __restrict__ shift,
    unsigned short* __restrict__ S16, float* __restrict__ swsum,
    float* __restrict__ degf) {
  int w = blockIdx.x * 4 + (threadIdx.x >> 6);
  if (w >= NN) return;
  int lane = threadIdx.x & 63;
  int o0 = off[w], o1 = off[w + 1];
  float ax = 1.f, ay = 1.f, bx = 0.f, by = 0.f;
  if (TRANS) {
    float2 sc = *(const float2*)&scale[lane * 2];
    float2 sh = *(const float2*)&shift[lane * 2];
    ax = sc.x; ay = sc.y; bx = sh.x; by = sh.y;
  }
  float accx = 0.f, accy = 0.f, ews = 0.f;
  for (int k = o0; k < o1; ++k) {
    int s = csr_src[k];
    float2 v = *(const float2*)&Xin[(size_t)s * H + lane * 2];
    if (TRANS) {
      float t0 = fmaf(ax, v.x, bx); v.x = t0 > 0.f ? t0 : 0.01f * t0;
      float t1 = fmaf(ay, v.y, by); v.y = t1 > 0.f ? t1 : 0.01f * t1;
    }
    accx += v.x; accy += v.y;
    ews += csr_ew[k];
  }
  unsigned int pk = ((unsigned int)f2bf(accy) << 16) | f2bf(accx);
  *(unsigned int*)&S16[(size_t)w * H + lane * 2] = pk;
  if (lane == 0) { swsum[w] = ews; degf[w] = (float)(o1 - o0); }
}

// ---------------- node GEMM (bf16 MFMA) + residual + BN partials ----------------
// out = S@W + deg*(bm+be) + swsum*We + resid(in); resid: TRANS ? lrelu(a*in+b) : in

template <bool TRANS>
__global__ __launch_bounds__(256) void k_gemm(
    const unsigned short* __restrict__ S16, const float* __restrict__ Xin,
    float* __restrict__ Xout, const unsigned short* __restrict__ Wt,
    const float* __restrict__ bm, const float* __restrict__ be,
    const float* __restrict__ We,
    const float* __restrict__ scale, const float* __restrict__ shift,
    const float* __restrict__ swsum, const float* __restrict__ degf,
    float* __restrict__ partials) {
  __shared__ unsigned short sA[128][40];
  __shared__ unsigned short sB[128][40];
  __shared__ float st[2][8][128];
  int tid = threadIdx.x;
  int w = tid >> 6, lane = tid & 63;
  int l15 = lane & 15, quad = lane >> 4;
  int wr = (w >> 1) * 64, wc = (w & 1) * 64;
  int rowbase = blockIdx.x * 128;
  f32x4 acc[4][4];
#pragma unroll
  for (int i = 0; i < 4; i++)
#pragma unroll
    for (int j = 0; j < 4; j++) acc[i][j] = (f32x4){0.f, 0.f, 0.f, 0.f};

  int arow = tid >> 1, ah = (tid & 1) * 16;  // 128 rows x 32 k per step
  int4 pa[2], pb[2];
  {
    int gr = rowbase + arow;
    if (gr < NN) {
      pa[0] = *(const int4*)&S16[(size_t)gr * H + ah];
      pa[1] = *(const int4*)&S16[(size_t)gr * H + ah + 8];
    } else {
      pa[0] = make_int4(0, 0, 0, 0); pa[1] = make_int4(0, 0, 0, 0);
    }
    pb[0] = *(const int4*)&Wt[(size_t)arow * H + ah];
    pb[1] = *(const int4*)&Wt[(size_t)arow * H + ah + 8];
  }
  for (int step = 0; step < 4; ++step) {
    *(int4*)&sA[arow][ah] = pa[0];
    *(int4*)&sA[arow][ah + 8] = pa[1];
    *(int4*)&sB[arow][ah] = pb[0];
    *(int4*)&sB[arow][ah + 8] = pb[1];
    __syncthreads();
    if (step + 1 < 4) {
      int kn = (step + 1) * 32;
      int gr = rowbase + arow;
      if (gr < NN) {
        pa[0] = *(const int4*)&S16[(size_t)gr * H + kn + ah];
        pa[1] = *(const int4*)&S16[(size_t)gr * H + kn + ah + 8];
      } else {
        pa[0] = make_int4(0, 0, 0, 0); pa[1] = make_int4(0, 0, 0, 0);
      }
      pb[0] = *(const int4*)&Wt[(size_t)arow * H + kn + ah];
      pb[1] = *(const int4*)&Wt[(size_t)arow * H + kn + ah + 8];
    }
    short8 af[4], bfr[4];
#pragma unroll
    for (int mt = 0; mt < 4; ++mt)
      af[mt] = *(const short8*)&sA[wr + mt * 16 + l15][quad * 8];
#pragma unroll
    for (int nt = 0; nt < 4; ++nt)
      bfr[nt] = *(const short8*)&sB[wc + nt * 16 + l15][quad * 8];
#pragma unroll
    for (int mt = 0; mt < 4; ++mt)
#pragma unroll
      for (int nt = 0; nt < 4; ++nt)
        acc[mt][nt] = __builtin_amdgcn_mfma_f32_16x16x32_bf16(
            af[mt], bfr[nt], acc[mt][nt], 0, 0, 0);
    __syncthreads();
  }
  // epilogue
  int col4[4];
  float cb4[4], we4[4], sc4[4], sh4[4], ps[4], pq[4];
#pragma unroll
  for (int nt = 0; nt < 4; ++nt) {
    int col = wc + nt * 16 + l15;
    col4[nt] = col;
    cb4[nt] = bm[col] + be[col];
    we4[nt] = We[col];
    if (TRANS) { sc4[nt] = scale[col]; sh4[nt] = shift[col]; }
    ps[nt] = 0.f; pq[nt] = 0.f;
  }
#pragma unroll
  for (int mt = 0; mt < 4; ++mt) {
#pragma unroll
    for (int r = 0; r < 4; ++r) {
      int n = rowbase + wr + mt * 16 + quad * 4 + r;
      if (n < NN) {
        float dg = degf[n], sw = swsum[n];
#pragma unroll
        for (int nt = 0; nt < 4; ++nt) {
          float rr = Xin[(size_t)n * H + col4[nt]];
          if (TRANS) {
            float t = fmaf(sc4[nt], rr, sh4[nt]);
            rr = t > 0.f ? t : 0.01f * t;
          }
          float o = acc[mt][nt][r] + dg * cb4[nt] + sw * we4[nt] + rr;
          Xout[(size_t)n * H + col4[nt]] = o;
          ps[nt] += o; pq[nt] += o * o;
        }
      }
    }
  }
  int slot = (w >> 1) * 4 + quad;
#pragma unroll
  for (int nt = 0; nt < 4; ++nt) {
    st[0][slot][col4[nt]] = ps[nt];
    st[1][slot][col4[nt]] = pq[nt];
  }
  __syncthreads();
  int plane = tid >> 7, col = tid & 127;
  float s = 0.f;
#pragma unroll
  for (int y = 0; y < 8; y++) s += st[plane][y][col];
  partials[(size_t)blockIdx.x * 256 + tid] = s;
}

// ---------------- BN stats finish: one block per column ----------------

__global__ __launch_bounds__(256) void k_bnstats(
    const float* __restrict__ partials, const float* __restrict__ g,
    const float* __restrict__ beta, float* __restrict__ scale,
    float* __restrict__ shift) {
  __shared__ float rs[256], rq[256];
  int j = blockIdx.x;  // column
  int t = threadIdx.x;
  float as = 0.f, aq = 0.f;
  for (int b = t; b < NB_GEMM; b += 256) {
    as += partials[(size_t)b * 256 + j];
    aq += partials[(size_t)b * 256 + 128 + j];
  }
  rs[t] = as; rq[t] = aq;
  __syncthreads();
  for (int s = 128; s > 0; s >>= 1) {
    if (t < s) { rs[t] += rs[t + s]; rq[t] += rq[t + s]; }
    __syncthreads();
  }
  if (t == 0) {
    float mean = rs[0] / (float)NN;
    float var = rq[0] / (float)NN - mean * mean;
    float a = g[j] * rsqrtf(var + EPS);
    scale[j] = a;
    shift[j] = beta[j] - mean * a;
  }
}

// ---------------- edge predict (one wave per edge) ----------------

__global__ __launch_bounds__(256) void k_pred(
    const int* __restrict__ emask, const int* __restrict__ EI,
    const float* __restrict__ XINI, const float* __restrict__ X,
    const float* __restrict__ scale, const float* __restrict__ shift,
    float* __restrict__ out) {
  int i = blockIdx.x * 4 + (threadIdx.x >> 6);
  if (i >= E_PRED) return;
  int lane = threadIdx.x & 63;
  int m = emask[i];
  int p0 = EI[m];
  int p1 = EI[E_TOT + m];
  float2 a = *(const float2*)&XINI[(size_t)p0 * H + lane * 2];
  float2 b = *(const float2*)&X[(size_t)p1 * H + lane * 2];
  float2 sc = *(const float2*)&scale[lane * 2];
  float2 sh = *(const float2*)&shift[lane * 2];
  float v = a.x * fmaf(sc.x, b.x, sh.x) + a.y * fmaf(sc.y, b.y, sh.y);
#pragma unroll
  for (int mm = 32; mm > 0; mm >>= 1) v += __shfl_xor(v, mm, 64);
  if (lane == 0) out[i] = 1.f / (1.f + expf(-v * (1.f / 128.f)));
}

// ---------------- launcher ----------------

extern "C" void kernel_launch(void* const* d_in, const int* in_sizes, int n_in,
                              void* d_out, int out_size, void* d_ws, size_t ws_size,
                              hipStream_t stream) {
  const float* qf    = (const float*)d_in[0];
  const float* lf    = (const float*)d_in[1];
  const int*   EI    = (const int*)d_in[2];
  const int*   emask = (const int*)d_in[3];
  const int*   ecs   = (const int*)d_in[4];
  const float* ewt   = (const float*)d_in[5];
  const float* Wq    = (const float*)d_in[6];
  const float* bq    = (const float*)d_in[7];
  const float* Wl    = (const float*)d_in[8];
  const float* bl    = (const float*)d_in[9];
  const float* Wem   = (const float*)d_in[10];
  const float* bem   = (const float*)d_in[11];
  const float* W1m   = (const float*)d_in[12];
  const float* b1m   = (const float*)d_in[13];
  const float* W1e   = (const float*)d_in[14];
  const float* b1e   = (const float*)d_in[15];
  const float* W2m   = (const float*)d_in[16];
  const float* b2m   = (const float*)d_in[17];
  const float* W2e   = (const float*)d_in[18];
  const float* b2e   = (const float*)d_in[19];
  const float* g1    = (const float*)d_in[20];
  const float* beta1 = (const float*)d_in[21];
  const float* g2    = (const float*)d_in[22];
  const float* beta2 = (const float*)d_in[23];
  float* out = (float*)d_out;

  char* p = (char*)d_ws;
  auto alloc = [&](size_t bytes) -> void* {
    void* r = (void*)p;
    p += (bytes + 255) & ~(size_t)255;
    return r;
  };
  float* XINI    = (float*)alloc((size_t)NN * H * 4);
  float* X       = (float*)alloc((size_t)NN * H * 4);
  unsigned short* S16 = (unsigned short*)alloc((size_t)NN * H * 2);
  float* ew      = (float*)alloc((size_t)E_SEE * 4);
  float* csr_ew  = (float*)alloc((size_t)E_SEE * 4);
  int*   csr_src = (int*)alloc((size_t)E_SEE * 4);
  int*   cnt     = (int*)alloc((size_t)NN * 4);
  int*   off     = (int*)alloc((size_t)(NN + 1) * 4);
  int*   cur     = (int*)alloc((size_t)NN * 4);
  int*   bsum    = (int*)alloc((size_t)NB_SCAN * 4);
  int*   boff    = (int*)alloc((size_t)NB_SCAN * 4);
  float* swsum   = (float*)alloc((size_t)NN * 4);
  float* degf    = (float*)alloc((size_t)NN * 4);
  float* partials= (float*)alloc((size_t)NB_GEMM * 256 * 4);
  float* scale1  = (float*)alloc(128 * 4);
  float* shift1  = (float*)alloc(128 * 4);
  float* scale2  = (float*)alloc(128 * 4);
  float* shift2  = (float*)alloc(128 * 4);
  unsigned short* Wqt = (unsigned short*)alloc((size_t)QD * H * 2);
  unsigned short* W1t = (unsigned short*)alloc((size_t)H * H * 2);
  unsigned short* W2t = (unsigned short*)alloc((size_t)H * H * 2);
  float* llmpart = (float*)alloc((size_t)NL * 8 * H * 4);

  hipMemsetAsync(cnt, 0, (size_t)NN * 4, stream);
  hipMemsetAsync(cur, 0, (size_t)NN * 4, stream);

  int ebl = (E_SEE + 255) / 256;
  k_prep<<<320, 256, 0, stream>>>(Wq, W1m, W2m, Wqt, W1t, W2t);
  k_ew_hist<<<ebl, 256, 0, stream>>>(ecs, EI, ewt, Wem, bem, ew, cnt);
  k_scan_block<<<NB_SCAN, 256, 0, stream>>>(cnt, bsum);
  k_scan_top<<<1, 512, 0, stream>>>(bsum, boff);
  k_scan_write<<<NB_SCAN, 256, 0, stream>>>(cnt, boff, off);
  k_fill<<<ebl, 256, 0, stream>>>(ecs, EI, ew, off, cur, csr_src, csr_ew);

  k_llm_part<<<NL * 8, 128, 0, stream>>>(lf, Wl, llmpart);
  k_llm_comb<<<(NL * H + 255) / 256, 256, 0, stream>>>(llmpart, bl, XINI);
  k_xini<<<NB_XINI, 256, 0, stream>>>(qf, Wqt, bq, XINI);

  int segbl = (NN + 3) / 4;
  // layer 1
  k_seg<false><<<segbl, 256, 0, stream>>>(XINI, off, csr_src, csr_ew,
                                          nullptr, nullptr, S16, swsum, degf);
  k_gemm<false><<<NB_GEMM, 256, 0, stream>>>(S16, XINI, X, W1t, b1m, b1e, W1e,
                                             nullptr, nullptr, swsum, degf, partials);
  k_bnstats<<<H, 256, 0, stream>>>(partials, g1, beta1, scale1, shift1);
  // layer 2 (BN1+lrelu folded into gather & residual)
  k_seg<true><<<segbl, 256, 0, stream>>>(X, off, csr_src, csr_ew,
                                         scale1, shift1, S16, swsum, degf);
  k_gemm<true><<<NB_GEMM, 256, 0, stream>>>(S16, X, X, W2t, b2m, b2e, W2e,
                                            scale1, shift1, swsum, degf, partials);
  k_bnstats<<<H, 256, 0, stream>>>(partials, g2, beta2, scale2, shift2);
  // predict (BN2 folded in)
  int pbl = (E_PRED + 3) / 4;
  k_pred<<<pbl, 256, 0, stream>>>(emask, EI, XINI, X, scale2, shift2, out);
}